// Round 4
// baseline (60.410 us; speedup 1.0000x reference)
//
#include <hip/hip_runtime.h>

constexpr int NC = 16;        // n_cgs
constexpr int NP = 256;       // npair
constexpr int PITCH = 268;    // LDS row pitch (floats): 268%8==4 -> 8 row-phases; 16B-aligned
constexpr int NATOMS = 512;
constexpr int NB = 128;
constexpr int WROW = NP + NP * NP;  // 65792 floats per W row

// ---------------------------------------------------------------------------
// Kernel A: stream W2 in (atom, 16-row chunk) tiles.
//   rows p in [16*chunk, +16): p&15 = row offset d, p>>4 = chunk.
//   P[d][q]   = W2[16*chunk + d][q]               (permuted copy -> LDS)
//   R[q]      = sum_d P[d][q]                     (chunk column sums)
//   wcd_part[chunk][n][d*16+c] = qfold(P)[c][d]
//        qfold(X)[c][d] = sum_qi X[d][16qi+c] - sum_qj X[d][16c+qj]
//   colsum[chunk][n][q] = R[q]   (the -delta(d,chunk)*qfold(R) lands in kB)
// Absorbs the soft_assign / xyz output copies.
// ---------------------------------------------------------------------------
__global__ __launch_bounds__(256, 6) void k_stream(const float* __restrict__ W,
                                                   const float* __restrict__ soft_assign,
                                                   const float* __restrict__ xyz,
                                                   float* __restrict__ wcd_part,
                                                   float* __restrict__ colsum,
                                                   float* __restrict__ out_sa,
                                                   float* __restrict__ out_xyz) {
    __shared__ float Hp[20][PITCH];   // rows 0..15: P[d][q]; rows 16..19: per-wave hn[q]
    const int bid = blockIdx.x;
    const int n = bid >> 4;
    const int chunk = bid & 15;
    const int t = threadIdx.x;
    const int s = t >> 6;    // wave id: rows 16*chunk + 4s + k
    const int q4 = t & 63;   // float4 column group

    // absorbed output copies (tiny, overlapped with W stream)
    if (t < 32) {
        ((float4*)out_sa)[bid * 32 + t] = ((const float4*)soft_assign)[bid * 32 + t];
    } else if (t < 38) {
        ((float4*)out_xyz)[bid * 6 + (t - 32)] = ((const float4*)xyz)[bid * 6 + (t - 32)];
    }

    // 4 rows x 4 cols, fully coalesced (1 KB per wave instruction), imm offsets
    const float4* __restrict__ wp =
        (const float4*)W + ((size_t)(n * 16448 + 64 + (chunk * 16 + s * 4) * 64 + q4));
    const float4 v0 = wp[0];
    const float4 v1 = wp[64];
    const float4 v2 = wp[128];
    const float4 v3 = wp[192];

    // scatter: P[4s+k][4q4..+3] = v_k   (contiguous per wave -> conflict-free)
    {
        float* lp = &Hp[4 * s][4 * q4];
        *(float4*)(lp + 0 * PITCH) = v0;
        *(float4*)(lp + 1 * PITCH) = v1;
        *(float4*)(lp + 2 * PITCH) = v2;
        *(float4*)(lp + 3 * PITCH) = v3;
        float4 hn;
        hn.x = (v0.x + v1.x) + (v2.x + v3.x);
        hn.y = (v0.y + v1.y) + (v2.y + v3.y);
        hn.z = (v0.z + v1.z) + (v2.z + v3.z);
        hn.w = (v0.w + v1.w) + (v2.w + v3.w);
        *(float4*)(&Hp[16 + s][4 * q4]) = hn;
    }
    __syncthreads();

    if (t < 64) {
        // wave 0: q-fold of P.  lane -> (d = t>>2, c4 = t&3), c = 4*c4+j
        const int d = t >> 2, c4 = t & 3;
        const float* __restrict__ rowp = &Hp[d][0];
        float4 ap;
        ap.x = 0.f; ap.y = 0.f; ap.z = 0.f; ap.w = 0.f;
#pragma unroll
        for (int qi = 0; qi < 16; ++qi) {
            const float4 pv = *(const float4*)(rowp + qi * 16 + 4 * c4);
            ap.x += pv.x; ap.y += pv.y; ap.z += pv.z; ap.w += pv.w;
        }
        float am[4];
#pragma unroll
        for (int j = 0; j < 4; ++j) {
            const float* mp = rowp + (4 * c4 + j) * 16;
            const float4 a = *(const float4*)(mp);
            const float4 b = *(const float4*)(mp + 4);
            const float4 c = *(const float4*)(mp + 8);
            const float4 e = *(const float4*)(mp + 12);
            am[j] = (((a.x + a.y) + (a.z + a.w)) + ((b.x + b.y) + (b.z + b.w))) +
                    (((c.x + c.y) + (c.z + c.w)) + ((e.x + e.y) + (e.z + e.w)));
        }
        float4 r;
        r.x = ap.x - am[0];
        r.y = ap.y - am[1];
        r.z = ap.z - am[2];
        r.w = ap.w - am[3];
        // lane t holds (c,d) block at float4 index t of this (chunk,n) tile
        ((float4*)wcd_part)[(size_t)(chunk * NATOMS + n) * 64 + t] = r;
    } else if (t < 128) {
        // wave 1: column sums R[q] = sum_s hn_s[q]
        const int l = t - 64;
        const float4 a = *(const float4*)(&Hp[16][4 * l]);
        const float4 b = *(const float4*)(&Hp[17][4 * l]);
        const float4 c = *(const float4*)(&Hp[18][4 * l]);
        const float4 e = *(const float4*)(&Hp[19][4 * l]);
        float4 r;
        r.x = (a.x + b.x) + (c.x + e.x);
        r.y = (a.y + b.y) + (c.y + e.y);
        r.z = (a.z + b.z) + (c.z + e.z);
        r.w = (a.w + b.w) + (c.w + e.w);
        ((float4*)colsum)[(size_t)(chunk * NATOMS + n) * 64 + l] = r;
    }
}

// ---------------------------------------------------------------------------
// Kernel B: per atom n:
//   wcd[n][d*16+c] = sum_chunk wcd_part[chunk][n][d*16+c] - qfold(R_d)[c]
//   where R_d = colsum[chunk=d][n].  Plus w1c from W's first 256 floats.
// ---------------------------------------------------------------------------
__global__ __launch_bounds__(256) void k_sum(const float* __restrict__ wcd_part,
                                             const float* __restrict__ colsum,
                                             const float* __restrict__ W,
                                             float* __restrict__ wcd,
                                             float* __restrict__ w1c) {
    __shared__ float Rl[16][PITCH];
    const int n = blockIdx.x;
    const int t = threadIdx.x;

#pragma unroll
    for (int ch = 0; ch < 16; ++ch)
        Rl[ch][t] = colsum[(size_t)(ch * NATOMS + n) * NP + t];
    __syncthreads();

    const int d = t >> 4, c = t & 15;
    float acc = 0.f;
#pragma unroll
    for (int ch = 0; ch < 16; ++ch)
        acc += wcd_part[(size_t)(ch * NATOMS + n) * NP + t];
    float rp = 0.f, rm = 0.f;
#pragma unroll
    for (int qi = 0; qi < 16; ++qi) rp += Rl[d][qi * 16 + c];
#pragma unroll
    for (int qj = 0; qj < 16; ++qj) rm += Rl[d][c * 16 + qj];
    wcd[n * NP + t] = acc - (rp - rm);

    if (t < NC) {
        const float* __restrict__ W1 = W + (size_t)n * WROW;
        float a1 = 0.f;
#pragma unroll
        for (int pi = 0; pi < NC; ++pi) a1 += W1[pi * NC + t];
#pragma unroll
        for (int pj = 0; pj < NC; ++pj) a1 -= W1[t * NC + pj];
        w1c[n * NC + t] = a1;
    }
}

// ---------------------------------------------------------------------------
// Kernel C: per-batch reconstruction (one 512-thread block per batch).
// ---------------------------------------------------------------------------
__global__ __launch_bounds__(512) void k_recon(const float* __restrict__ cg_xyz,
                                               const float* __restrict__ assign_norm,
                                               const int* __restrict__ assign_idx,
                                               const float* __restrict__ wcd,
                                               const float* __restrict__ w1c,
                                               float* __restrict__ out_recon) {
    __shared__ float xs[NC][4];
    __shared__ float cxs[NP][4];
    __shared__ float part[8][48];
    __shared__ float cgo[48];
    const int b = blockIdx.x;
    const int t = threadIdx.x;

    if (t < NC * 3) xs[t / 3][t % 3] = cg_xyz[(size_t)b * NC * 3 + t];
    __syncthreads();
    if (t < NP) {
        const int c = t & 15, d = t >> 4;
        const float ax = xs[c][0], ay = xs[c][1], az = xs[c][2];
        const float bx = xs[d][0], by = xs[d][1], bz = xs[d][2];
        cxs[t][0] = ay * bz - az * by;
        cxs[t][1] = az * bx - ax * bz;
        cxs[t][2] = ax * by - ay * bx;
        cxs[t][3] = 0.f;
    }
    __syncthreads();

    const int n = t;
    float dx0 = 0.f, dx1 = 0.f, dx2 = 0.f;
    const float4* __restrict__ wrow = (const float4*)(wcd + n * NP);
#pragma unroll 8
    for (int k4 = 0; k4 < 64; ++k4) {
        const float4 w = wrow[k4];
        const float4 c0 = *(const float4*)(&cxs[k4 * 4 + 0][0]);
        const float4 c1 = *(const float4*)(&cxs[k4 * 4 + 1][0]);
        const float4 c2 = *(const float4*)(&cxs[k4 * 4 + 2][0]);
        const float4 c3 = *(const float4*)(&cxs[k4 * 4 + 3][0]);
        dx0 += w.x * c0.x + w.y * c1.x + w.z * c2.x + w.w * c3.x;
        dx1 += w.x * c0.y + w.y * c1.y + w.z * c2.y + w.w * c3.y;
        dx2 += w.x * c0.z + w.y * c1.z + w.z * c2.z + w.w * c3.z;
    }
    const float* __restrict__ w1row = w1c + n * NC;
#pragma unroll
    for (int c = 0; c < NC; ++c) {
        const float wv = w1row[c];
        dx0 += wv * xs[c][0]; dx1 += wv * xs[c][1]; dx2 += wv * xs[c][2];
    }

    float an[NC];
    const float4* __restrict__ anr =
        (const float4*)(assign_norm + ((size_t)b * NATOMS + n) * NC);
#pragma unroll
    for (int i = 0; i < 4; ++i) {
        const float4 v = anr[i];
        an[4 * i + 0] = v.x; an[4 * i + 1] = v.y; an[4 * i + 2] = v.z; an[4 * i + 3] = v.w;
    }
    const int wv_ = t >> 6;
#pragma unroll
    for (int j = 0; j < NC; ++j) {
        float p0 = an[j] * dx0, p1 = an[j] * dx1, p2 = an[j] * dx2;
#pragma unroll
        for (int sh = 1; sh < 64; sh <<= 1) {
            p0 += __shfl_xor(p0, sh);
            p1 += __shfl_xor(p1, sh);
            p2 += __shfl_xor(p2, sh);
        }
        if ((t & 63) == 0) {
            part[wv_][j * 3 + 0] = p0;
            part[wv_][j * 3 + 1] = p1;
            part[wv_][j * 3 + 2] = p2;
        }
    }
    __syncthreads();
    if (t < 48) {
        float sm = 0.f;
#pragma unroll
        for (int w8 = 0; w8 < 8; ++w8) sm += part[w8][t];
        cgo[t] = sm;
    }
    __syncthreads();

    const int ci = assign_idx[n];
    const float r0 = xs[ci][0] - cgo[ci * 3 + 0] + dx0;
    const float r1 = xs[ci][1] - cgo[ci * 3 + 1] + dx1;
    const float r2 = xs[ci][2] - cgo[ci * 3 + 2] + dx2;
    const size_t ob = ((size_t)b * NATOMS + n) * 3;
    out_recon[ob + 0] = r0;
    out_recon[ob + 1] = r1;
    out_recon[ob + 2] = r2;
}

extern "C" void kernel_launch(void* const* d_in, const int* in_sizes, int n_in,
                              void* d_out, int out_size, void* d_ws, size_t ws_size,
                              hipStream_t stream) {
    (void)in_sizes; (void)n_in; (void)out_size; (void)ws_size;
    const float* soft_assign = (const float*)d_in[0];
    const float* xyz         = (const float*)d_in[1];
    const float* cg_xyz      = (const float*)d_in[2];
    const float* assign_norm = (const float*)d_in[3];
    const float* W           = (const float*)d_in[4];
    const int*   assign_idx  = (const int*)d_in[5];

    float* out       = (float*)d_out;
    float* out_sa    = out;                                   // 128*512*16
    float* out_xyz   = out + (size_t)NB * NATOMS * NC;        // 128*512*3
    float* out_recon = out_xyz + (size_t)NB * NATOMS * 3;

    float* wcd_part = (float*)d_ws;                           // 16*512*256
    float* colsum   = wcd_part + (size_t)16 * NATOMS * NP;    // 16*512*256
    float* wcd      = colsum + (size_t)16 * NATOMS * NP;      // 512*256
    float* w1c      = wcd + (size_t)NATOMS * NP;              // 512*16

    k_stream<<<dim3(NATOMS * 16), dim3(256), 0, stream>>>(W, soft_assign, xyz,
                                                          wcd_part, colsum,
                                                          out_sa, out_xyz);
    k_sum<<<dim3(NATOMS), dim3(256), 0, stream>>>(wcd_part, colsum, W, wcd, w1c);
    k_recon<<<dim3(NB), dim3(512), 0, stream>>>(cg_xyz, assign_norm, assign_idx,
                                                wcd, w1c, out_recon);
}

// Round 5
// 55.376 us; speedup vs baseline: 1.0909x; 1.0909x over previous
//
#include <hip/hip_runtime.h>

constexpr int NC = 16;        // n_cgs
constexpr int NP = 256;       // npair
constexpr int PITCH = 264;    // LDS row pitch (floats)
constexpr int NATOMS = 512;
constexpr int NB = 128;
constexpr int WROW = NP + NP * NP;  // 65792 floats per W row

// ---------------------------------------------------------------------------
// Kernel A: fill-style W2 stream. grid = 512 atoms x 2 row-halves, 256 thr.
// Thread t owns column q=t. It streams 128 rows (fully unrolled b32 loads)
// into 16 register accumulators:
//   h[d] = sum_{p: p&15==d} W2[p][t]  -  sum_{p: p>>4==d} W2[p][t]
// (the minus part via per-16-row-group sums hn[g]; p>>4 = half*8+g).
// One barrier, then the q-fold (d=t>>4, c=t&15):
//   part[half][n][d*16+c] = sum_qi H[d][16qi+c] - sum_qj H[d][16c+qj]
// Absorbs the soft_assign / xyz output copies.
// ---------------------------------------------------------------------------
__global__ __launch_bounds__(256) void k_stream(const float* __restrict__ W,
                                                const float* __restrict__ soft_assign,
                                                const float* __restrict__ xyz,
                                                float* __restrict__ wcd_part,
                                                float* __restrict__ out_sa,
                                                float* __restrict__ out_xyz) {
    __shared__ float Hl[NC][PITCH];   // 16.9 KB
    const int bid = blockIdx.x;
    const int n = bid >> 1;
    const int half = bid & 1;
    const int t = threadIdx.x;

    // absorbed output copies: 1 float4 of sa per thread, 48 of xyz per block
    ((float4*)out_sa)[bid * 256 + t] = ((const float4*)soft_assign)[bid * 256 + t];
    if (t < 48) {
        ((float4*)out_xyz)[bid * 48 + t] = ((const float4*)xyz)[bid * 48 + t];
    }

    // stream 128 rows of column t (wave reads 256B contiguous per instr)
    const float* __restrict__ wp =
        W + (size_t)n * WROW + NP + (size_t)(half * 128) * NP + t;
    float h[NC];
#pragma unroll
    for (int d = 0; d < NC; ++d) h[d] = 0.f;
    float hn[8];
#pragma unroll
    for (int g = 0; g < 8; ++g) {
        float s = 0.f;
#pragma unroll
        for (int i = 0; i < 16; ++i) {
            const float v = wp[(size_t)(g * 16 + i) * NP];
            h[i] += v;
            s += v;
        }
        hn[g] = s;
    }
    if (half == 0) {
        h[0] -= hn[0]; h[1] -= hn[1]; h[2] -= hn[2]; h[3] -= hn[3];
        h[4] -= hn[4]; h[5] -= hn[5]; h[6] -= hn[6]; h[7] -= hn[7];
    } else {
        h[8]  -= hn[0]; h[9]  -= hn[1]; h[10] -= hn[2]; h[11] -= hn[3];
        h[12] -= hn[4]; h[13] -= hn[5]; h[14] -= hn[6]; h[15] -= hn[7];
    }

    // H -> LDS (consecutive t per wave: conflict-free)
#pragma unroll
    for (int d = 0; d < NC; ++d) Hl[d][t] = h[d];
    __syncthreads();

    // q-fold: one output per thread, coalesced store
    {
        const int d = t >> 4, c = t & 15;
        float rp = 0.f, rm = 0.f;
#pragma unroll
        for (int qi = 0; qi < NC; ++qi) rp += Hl[d][qi * NC + c];
#pragma unroll
        for (int qj = 0; qj < NC; ++qj) rm += Hl[d][c * NC + qj];
        wcd_part[((size_t)half * NATOMS + n) * NP + t] = rp - rm;
    }
}

// ---------------------------------------------------------------------------
// Kernel B: wcd = part0 + part1; w1c from W's first 256 floats per atom.
// ---------------------------------------------------------------------------
__global__ __launch_bounds__(256) void k_sum(const float* __restrict__ wcd_part,
                                             const float* __restrict__ W,
                                             float* __restrict__ wcd,
                                             float* __restrict__ w1c) {
    const int n = blockIdx.x;
    const int t = threadIdx.x;
    const float a = wcd_part[(size_t)n * NP + t] +
                    wcd_part[((size_t)NATOMS + n) * NP + t];
    wcd[n * NP + t] = a;
    if (t < NC) {
        const float* __restrict__ W1 = W + (size_t)n * WROW;
        float a1 = 0.f;
#pragma unroll
        for (int pi = 0; pi < NC; ++pi) a1 += W1[pi * NC + t];
#pragma unroll
        for (int pj = 0; pj < NC; ++pj) a1 -= W1[t * NC + pj];
        w1c[n * NC + t] = a1;
    }
}

// ---------------------------------------------------------------------------
// Kernel C: per-batch reconstruction (one 512-thread block per batch).
// ---------------------------------------------------------------------------
__global__ __launch_bounds__(512) void k_recon(const float* __restrict__ cg_xyz,
                                               const float* __restrict__ assign_norm,
                                               const int* __restrict__ assign_idx,
                                               const float* __restrict__ wcd,
                                               const float* __restrict__ w1c,
                                               float* __restrict__ out_recon) {
    __shared__ float xs[NC][4];
    __shared__ float cxs[NP][4];
    __shared__ float part[8][48];
    __shared__ float cgo[48];
    const int b = blockIdx.x;
    const int t = threadIdx.x;

    if (t < NC * 3) xs[t / 3][t % 3] = cg_xyz[(size_t)b * NC * 3 + t];
    __syncthreads();
    if (t < NP) {
        const int c = t & 15, d = t >> 4;
        const float ax = xs[c][0], ay = xs[c][1], az = xs[c][2];
        const float bx = xs[d][0], by = xs[d][1], bz = xs[d][2];
        cxs[t][0] = ay * bz - az * by;
        cxs[t][1] = az * bx - ax * bz;
        cxs[t][2] = ax * by - ay * bx;
        cxs[t][3] = 0.f;
    }
    __syncthreads();

    const int n = t;
    float dx0 = 0.f, dx1 = 0.f, dx2 = 0.f;
    const float4* __restrict__ wrow = (const float4*)(wcd + n * NP);
#pragma unroll 8
    for (int k4 = 0; k4 < 64; ++k4) {
        const float4 w = wrow[k4];
        const float4 c0 = *(const float4*)(&cxs[k4 * 4 + 0][0]);
        const float4 c1 = *(const float4*)(&cxs[k4 * 4 + 1][0]);
        const float4 c2 = *(const float4*)(&cxs[k4 * 4 + 2][0]);
        const float4 c3 = *(const float4*)(&cxs[k4 * 4 + 3][0]);
        dx0 += w.x * c0.x + w.y * c1.x + w.z * c2.x + w.w * c3.x;
        dx1 += w.x * c0.y + w.y * c1.y + w.z * c2.y + w.w * c3.y;
        dx2 += w.x * c0.z + w.y * c1.z + w.z * c2.z + w.w * c3.z;
    }
    const float* __restrict__ w1row = w1c + n * NC;
#pragma unroll
    for (int c = 0; c < NC; ++c) {
        const float wv = w1row[c];
        dx0 += wv * xs[c][0]; dx1 += wv * xs[c][1]; dx2 += wv * xs[c][2];
    }

    float an[NC];
    const float4* __restrict__ anr =
        (const float4*)(assign_norm + ((size_t)b * NATOMS + n) * NC);
#pragma unroll
    for (int i = 0; i < 4; ++i) {
        const float4 v = anr[i];
        an[4 * i + 0] = v.x; an[4 * i + 1] = v.y; an[4 * i + 2] = v.z; an[4 * i + 3] = v.w;
    }
    const int wv_ = t >> 6;
#pragma unroll
    for (int j = 0; j < NC; ++j) {
        float p0 = an[j] * dx0, p1 = an[j] * dx1, p2 = an[j] * dx2;
#pragma unroll
        for (int sh = 1; sh < 64; sh <<= 1) {
            p0 += __shfl_xor(p0, sh);
            p1 += __shfl_xor(p1, sh);
            p2 += __shfl_xor(p2, sh);
        }
        if ((t & 63) == 0) {
            part[wv_][j * 3 + 0] = p0;
            part[wv_][j * 3 + 1] = p1;
            part[wv_][j * 3 + 2] = p2;
        }
    }
    __syncthreads();
    if (t < 48) {
        float sm = 0.f;
#pragma unroll
        for (int w8 = 0; w8 < 8; ++w8) sm += part[w8][t];
        cgo[t] = sm;
    }
    __syncthreads();

    const int ci = assign_idx[n];
    const float r0 = xs[ci][0] - cgo[ci * 3 + 0] + dx0;
    const float r1 = xs[ci][1] - cgo[ci * 3 + 1] + dx1;
    const float r2 = xs[ci][2] - cgo[ci * 3 + 2] + dx2;
    const size_t ob = ((size_t)b * NATOMS + n) * 3;
    out_recon[ob + 0] = r0;
    out_recon[ob + 1] = r1;
    out_recon[ob + 2] = r2;
}

extern "C" void kernel_launch(void* const* d_in, const int* in_sizes, int n_in,
                              void* d_out, int out_size, void* d_ws, size_t ws_size,
                              hipStream_t stream) {
    (void)in_sizes; (void)n_in; (void)out_size; (void)ws_size;
    const float* soft_assign = (const float*)d_in[0];
    const float* xyz         = (const float*)d_in[1];
    const float* cg_xyz      = (const float*)d_in[2];
    const float* assign_norm = (const float*)d_in[3];
    const float* W           = (const float*)d_in[4];
    const int*   assign_idx  = (const int*)d_in[5];

    float* out       = (float*)d_out;
    float* out_sa    = out;                                   // 128*512*16
    float* out_xyz   = out + (size_t)NB * NATOMS * NC;        // 128*512*3
    float* out_recon = out_xyz + (size_t)NB * NATOMS * 3;

    float* wcd_part = (float*)d_ws;                           // 2*512*256
    float* wcd      = wcd_part + (size_t)2 * NATOMS * NP;     // 512*256
    float* w1c      = wcd + (size_t)NATOMS * NP;              // 512*16

    k_stream<<<dim3(NATOMS * 2), dim3(256), 0, stream>>>(W, soft_assign, xyz,
                                                         wcd_part, out_sa, out_xyz);
    k_sum<<<dim3(NATOMS), dim3(256), 0, stream>>>(wcd_part, W, wcd, w1c);
    k_recon<<<dim3(NB), dim3(512), 0, stream>>>(cg_xyz, assign_norm, assign_idx,
                                                wcd, w1c, out_recon);
}

// Round 6
// 52.743 us; speedup vs baseline: 1.1454x; 1.0499x over previous
//
#include <hip/hip_runtime.h>

constexpr int NC = 16;        // n_cgs
constexpr int NP = 256;       // npair
constexpr int PITCH = 264;    // LDS row pitch for k_stream fold
constexpr int NATOMS = 512;
constexpr int NB = 128;
constexpr int WROW = NP + NP * NP;  // 65792 floats per W row
constexpr int ANP = 21;       // an LDS pitch (21 coprime 32 -> conflict-free j-reads)
constexpr int DXP = 5;        // dx LDS pitch (5 coprime 32)

// ---------------------------------------------------------------------------
// Kernel A: fill-style W2 stream (identical math/structure to R5, verified).
// Thread t owns column q=t; streams 128 rows into 16 register accumulators.
// One barrier, then q-fold -> wcd_part[half][n][d*16+c].
// Absorbs: soft_assign/xyz output copies AND w1c (was kernel B).
// ---------------------------------------------------------------------------
__global__ __launch_bounds__(256) void k_stream(const float* __restrict__ W,
                                                const float* __restrict__ soft_assign,
                                                const float* __restrict__ xyz,
                                                float* __restrict__ wcd_part,
                                                float* __restrict__ w1c,
                                                float* __restrict__ out_sa,
                                                float* __restrict__ out_xyz) {
    __shared__ float Hl[NC][PITCH];   // 16.9 KB
    const int bid = blockIdx.x;
    const int n = bid >> 1;
    const int half = bid & 1;
    const int t = threadIdx.x;

    // absorbed output copies
    ((float4*)out_sa)[bid * 256 + t] = ((const float4*)soft_assign)[bid * 256 + t];
    if (t < 48) {
        ((float4*)out_xyz)[bid * 48 + t] = ((const float4*)xyz)[bid * 48 + t];
    }

    // w1c (absorbed from old k_sum): half==0 blocks, 16 threads, 1KB L2-hot row
    if (half == 0 && t < NC) {
        const float* __restrict__ W1 = W + (size_t)n * WROW;
        float a1 = 0.f;
#pragma unroll
        for (int pi = 0; pi < NC; ++pi) a1 += W1[pi * NC + t];
#pragma unroll
        for (int pj = 0; pj < NC; ++pj) a1 -= W1[t * NC + pj];
        w1c[n * NC + t] = a1;
    }

    // stream 128 rows of column t
    const float* __restrict__ wp =
        W + (size_t)n * WROW + NP + (size_t)(half * 128) * NP + t;
    float h[NC];
#pragma unroll
    for (int d = 0; d < NC; ++d) h[d] = 0.f;
    float hn[8];
#pragma unroll
    for (int g = 0; g < 8; ++g) {
        float s = 0.f;
#pragma unroll
        for (int i = 0; i < 16; ++i) {
            const float v = wp[(size_t)(g * 16 + i) * NP];
            h[i] += v;
            s += v;
        }
        hn[g] = s;
    }
    if (half == 0) {
        h[0] -= hn[0]; h[1] -= hn[1]; h[2] -= hn[2]; h[3] -= hn[3];
        h[4] -= hn[4]; h[5] -= hn[5]; h[6] -= hn[6]; h[7] -= hn[7];
    } else {
        h[8]  -= hn[0]; h[9]  -= hn[1]; h[10] -= hn[2]; h[11] -= hn[3];
        h[12] -= hn[4]; h[13] -= hn[5]; h[14] -= hn[6]; h[15] -= hn[7];
    }

#pragma unroll
    for (int d = 0; d < NC; ++d) Hl[d][t] = h[d];
    __syncthreads();

    {
        const int d = t >> 4, c = t & 15;
        float rp = 0.f, rm = 0.f;
#pragma unroll
        for (int qi = 0; qi < NC; ++qi) rp += Hl[d][qi * NC + c];
#pragma unroll
        for (int qj = 0; qj < NC; ++qj) rm += Hl[d][c * NC + qj];
        wcd_part[((size_t)half * NATOMS + n) * NP + t] = rp - rm;
    }
}

// ---------------------------------------------------------------------------
// Kernel B: dx partials.  grid = 128 batches x 4 m-quarters, 256 threads.
// Block (b,q): CX chunk m in [64q, 64q+64) in LDS (wave-uniform broadcast
// reads), each thread computes atoms {t, t+256} partial dx over the chunk,
// summing the two wcd_part halves inline.  q==0 adds the w1c*xs term.
// ---------------------------------------------------------------------------
__global__ __launch_bounds__(256) void k_dx(const float* __restrict__ cg_xyz,
                                            const float* __restrict__ wcd_part,
                                            const float* __restrict__ w1c,
                                            float* __restrict__ dxp) {
    __shared__ float xs[NC][4];
    __shared__ float cxs[64][4];
    const int b = blockIdx.x >> 2;
    const int q = blockIdx.x & 3;
    const int t = threadIdx.x;

    if (t < 48) xs[t / 3][t % 3] = cg_xyz[(size_t)b * NC * 3 + t];
    __syncthreads();
    if (t < 64) {
        const int m = q * 64 + t, c = m & 15, d = m >> 4;
        const float ax = xs[c][0], ay = xs[c][1], az = xs[c][2];
        const float bx = xs[d][0], by = xs[d][1], bz = xs[d][2];
        cxs[t][0] = ay * bz - az * by;
        cxs[t][1] = az * bx - ax * bz;
        cxs[t][2] = ax * by - ay * bx;
        cxs[t][3] = 0.f;
    }
    __syncthreads();

#pragma unroll
    for (int a = 0; a < 2; ++a) {
        const int n = a * 256 + t;
        const float4* __restrict__ w0 =
            (const float4*)(wcd_part + (size_t)n * NP + q * 64);
        const float4* __restrict__ w1 =
            (const float4*)(wcd_part + ((size_t)NATOMS + n) * NP + q * 64);
        float dx0 = 0.f, dx1 = 0.f, dx2 = 0.f;
#pragma unroll
        for (int k4 = 0; k4 < 16; ++k4) {
            const float4 wa = w0[k4];
            const float4 wb = w1[k4];
            float4 w;
            w.x = wa.x + wb.x; w.y = wa.y + wb.y;
            w.z = wa.z + wb.z; w.w = wa.w + wb.w;
            const float4 c0 = *(const float4*)(&cxs[k4 * 4 + 0][0]);
            const float4 c1 = *(const float4*)(&cxs[k4 * 4 + 1][0]);
            const float4 c2 = *(const float4*)(&cxs[k4 * 4 + 2][0]);
            const float4 c3 = *(const float4*)(&cxs[k4 * 4 + 3][0]);
            dx0 += w.x * c0.x + w.y * c1.x + w.z * c2.x + w.w * c3.x;
            dx1 += w.x * c0.y + w.y * c1.y + w.z * c2.y + w.w * c3.y;
            dx2 += w.x * c0.z + w.y * c1.z + w.z * c2.z + w.w * c3.z;
        }
        if (q == 0) {
            const float* __restrict__ w1r = w1c + n * NC;
#pragma unroll
            for (int c = 0; c < NC; ++c) {
                const float wv = w1r[c];
                dx0 += wv * xs[c][0]; dx1 += wv * xs[c][1]; dx2 += wv * xs[c][2];
            }
        }
        float* __restrict__ op = dxp + (((size_t)q * NB + b) * NATOMS + n) * 3;
        op[0] = dx0; op[1] = dx1; op[2] = dx2;
    }
}

// ---------------------------------------------------------------------------
// Kernel C: finish.  grid = 128 batches, 512 threads (one per atom).
//   dx[n] = sum_q dxp[q][b][n]; cgo via j-split reduction; final output.
// ---------------------------------------------------------------------------
__global__ __launch_bounds__(512) void k_finish(const float* __restrict__ cg_xyz,
                                                const float* __restrict__ assign_norm,
                                                const int* __restrict__ assign_idx,
                                                const float* __restrict__ dxp,
                                                float* __restrict__ out_recon) {
    __shared__ float an_l[NATOMS][ANP];   // 43.0 KB
    __shared__ float dxl[NATOMS][DXP];    // 10.2 KB
    __shared__ float xs[NC][4];
    __shared__ float cgo_l[NC][4];
    const int b = blockIdx.x;
    const int t = threadIdx.x;

    // an -> LDS (coalesced float4 reads, conflict-free b32 writes: 21 coprime 32)
    {
        const float4* __restrict__ anr =
            (const float4*)(assign_norm + ((size_t)b * NATOMS + t) * NC);
#pragma unroll
        for (int i = 0; i < 4; ++i) {
            const float4 v = anr[i];
            an_l[t][4 * i + 0] = v.x; an_l[t][4 * i + 1] = v.y;
            an_l[t][4 * i + 2] = v.z; an_l[t][4 * i + 3] = v.w;
        }
    }
    if (t < 48) xs[t / 3][t % 3] = cg_xyz[(size_t)b * NC * 3 + t];

    // dx = sum of the 4 partials
    float dx0, dx1, dx2;
    {
        const size_t s0 = (((size_t)0 * NB + b) * NATOMS + t) * 3;
        const size_t s1 = (((size_t)1 * NB + b) * NATOMS + t) * 3;
        const size_t s2 = (((size_t)2 * NB + b) * NATOMS + t) * 3;
        const size_t s3 = (((size_t)3 * NB + b) * NATOMS + t) * 3;
        dx0 = (dxp[s0 + 0] + dxp[s1 + 0]) + (dxp[s2 + 0] + dxp[s3 + 0]);
        dx1 = (dxp[s0 + 1] + dxp[s1 + 1]) + (dxp[s2 + 1] + dxp[s3 + 1]);
        dx2 = (dxp[s0 + 2] + dxp[s1 + 2]) + (dxp[s2 + 2] + dxp[s3 + 2]);
    }
    dxl[t][0] = dx0; dxl[t][1] = dx1; dxl[t][2] = dx2;
    __syncthreads();

    // cgo[j] = sum_i an[i][j] * dx[i]: thread (j = t>>5, g = t&31) covers
    // atoms i = g + 32k.  LDS reads conflict-free by pitch choice.
    {
        const int j = t >> 5, g = t & 31;
        float p0 = 0.f, p1 = 0.f, p2 = 0.f;
#pragma unroll
        for (int k = 0; k < 16; ++k) {
            const int i = g + 32 * k;
            const float a = an_l[i][j];
            p0 += a * dxl[i][0];
            p1 += a * dxl[i][1];
            p2 += a * dxl[i][2];
        }
#pragma unroll
        for (int s = 1; s < 32; s <<= 1) {
            p0 += __shfl_xor(p0, s);
            p1 += __shfl_xor(p1, s);
            p2 += __shfl_xor(p2, s);
        }
        if (g == 0) { cgo_l[j][0] = p0; cgo_l[j][1] = p1; cgo_l[j][2] = p2; }
    }
    __syncthreads();

    const int ci = assign_idx[t];
    const float r0 = xs[ci][0] - cgo_l[ci][0] + dx0;
    const float r1 = xs[ci][1] - cgo_l[ci][1] + dx1;
    const float r2 = xs[ci][2] - cgo_l[ci][2] + dx2;
    const size_t ob = ((size_t)b * NATOMS + t) * 3;
    out_recon[ob + 0] = r0;
    out_recon[ob + 1] = r1;
    out_recon[ob + 2] = r2;
}

extern "C" void kernel_launch(void* const* d_in, const int* in_sizes, int n_in,
                              void* d_out, int out_size, void* d_ws, size_t ws_size,
                              hipStream_t stream) {
    (void)in_sizes; (void)n_in; (void)out_size; (void)ws_size;
    const float* soft_assign = (const float*)d_in[0];
    const float* xyz         = (const float*)d_in[1];
    const float* cg_xyz      = (const float*)d_in[2];
    const float* assign_norm = (const float*)d_in[3];
    const float* W           = (const float*)d_in[4];
    const int*   assign_idx  = (const int*)d_in[5];

    float* out       = (float*)d_out;
    float* out_sa    = out;                                   // 128*512*16
    float* out_xyz   = out + (size_t)NB * NATOMS * NC;        // 128*512*3
    float* out_recon = out_xyz + (size_t)NB * NATOMS * 3;

    float* wcd_part = (float*)d_ws;                           // 2*512*256
    float* w1c      = wcd_part + (size_t)2 * NATOMS * NP;     // 512*16
    float* dxp      = w1c + (size_t)NATOMS * NC;              // 4*128*512*3

    k_stream<<<dim3(NATOMS * 2), dim3(256), 0, stream>>>(W, soft_assign, xyz,
                                                         wcd_part, w1c,
                                                         out_sa, out_xyz);
    k_dx<<<dim3(NB * 4), dim3(256), 0, stream>>>(cg_xyz, wcd_part, w1c, dxp);
    k_finish<<<dim3(NB), dim3(512), 0, stream>>>(cg_xyz, assign_norm, assign_idx,
                                                 dxp, out_recon);
}

// Round 7
// 44.697 us; speedup vs baseline: 1.3515x; 1.1800x over previous
//
#include <hip/hip_runtime.h>

constexpr int NC = 16;        // n_cgs
constexpr int NP = 256;       // npair
constexpr int PITCH = 264;    // LDS row pitch (floats)
constexpr int NATOMS = 512;
constexpr int NB = 128;
constexpr int WROW = NP + NP * NP;  // 65792 floats per W row
constexpr int ANP = 21;       // an LDS pitch (21 coprime 32)
constexpr int DXP = 5;        // dx LDS pitch (5 coprime 32)

#define F4ADD(a, v) do { (a).x += (v).x; (a).y += (v).y; (a).z += (v).z; (a).w += (v).w; } while (0)
#define F4SUB(a, v) do { (a).x -= (v).x; (a).y -= (v).y; (a).z -= (v).z; (a).w -= (v).w; } while (0)

// ---------------------------------------------------------------------------
// Kernel A: dwordx4 deep-stream of W2.  One block per atom; wave s owns rows
// [64s, 64s+64), lane l owns cols [4l, 4l+4).  64 float4 loads per thread,
// fully unrolled: every wave instruction reads a contiguous 1 KB row.
//   h4[d] += row (d = i&15);  hn4[g] += row (g = i>>4, p>>4 = 4s+g)
// Barrier -> combine 4 wave-partial H planes (conflict-free) -> q-fold
// (R5-verified) -> wcd[n][d*16+c].  Absorbs sa/xyz copies and w1c.
// ---------------------------------------------------------------------------
__global__ __launch_bounds__(256) void k_stream(const float* __restrict__ W,
                                                const float* __restrict__ soft_assign,
                                                const float* __restrict__ xyz,
                                                float* __restrict__ wcd,
                                                float* __restrict__ w1c,
                                                float* __restrict__ out_sa,
                                                float* __restrict__ out_xyz) {
    __shared__ float Hp[4][NC][PITCH];   // 67.6 KB -> 2 blocks/CU
    const int n = blockIdx.x;
    const int t = threadIdx.x;
    const int s = t >> 6;    // wave: rows [64s, 64s+64)
    const int l = t & 63;    // cols [4l, 4l+4)

    // absorbed output copies (2 float4 sa + <=96 float4 xyz per block)
    ((float4*)out_sa)[n * 512 + t]       = ((const float4*)soft_assign)[n * 512 + t];
    ((float4*)out_sa)[n * 512 + 256 + t] = ((const float4*)soft_assign)[n * 512 + 256 + t];
    if (t < 96) {
        ((float4*)out_xyz)[n * 96 + t] = ((const float4*)xyz)[n * 96 + t];
    }
    // w1c (L2-hot 1 KB row head)
    if (t < NC) {
        const float* __restrict__ W1 = W + (size_t)n * WROW;
        float a1 = 0.f;
#pragma unroll
        for (int pi = 0; pi < NC; ++pi) a1 += W1[pi * NC + t];
#pragma unroll
        for (int pj = 0; pj < NC; ++pj) a1 -= W1[t * NC + pj];
        w1c[n * NC + t] = a1;
    }

    // ---- stream 64 rows x 4 cols as float4 ----
    const float4* __restrict__ wp =
        (const float4*)W + ((size_t)n * 16448 + 64 + (size_t)(s * 64) * 64 + l);
    float4 h4[NC], hn4[4];
#pragma unroll
    for (int d = 0; d < NC; ++d) { h4[d].x = 0.f; h4[d].y = 0.f; h4[d].z = 0.f; h4[d].w = 0.f; }
#pragma unroll
    for (int g = 0; g < 4; ++g) { hn4[g].x = 0.f; hn4[g].y = 0.f; hn4[g].z = 0.f; hn4[g].w = 0.f; }
#pragma unroll
    for (int i = 0; i < 64; ++i) {
        const float4 v = wp[(size_t)i * 64];
        F4ADD(h4[i & 15], v);
        F4ADD(hn4[i >> 4], v);
    }
    // fold -delta(d, p>>4): p>>4 = 4s+g
    switch (s) {
      case 0:
#pragma unroll
        for (int k = 0; k < 4; ++k) F4SUB(h4[k], hn4[k]);
        break;
      case 1:
#pragma unroll
        for (int k = 0; k < 4; ++k) F4SUB(h4[4 + k], hn4[k]);
        break;
      case 2:
#pragma unroll
        for (int k = 0; k < 4; ++k) F4SUB(h4[8 + k], hn4[k]);
        break;
      default:
#pragma unroll
        for (int k = 0; k < 4; ++k) F4SUB(h4[12 + k], hn4[k]);
        break;
    }
    // per-wave H plane -> LDS (16-B contiguous per lane: conflict-free)
#pragma unroll
    for (int d = 0; d < NC; ++d) {
        *(float4*)(&Hp[s][d][4 * l]) = h4[d];
    }
    __syncthreads();

    // combine 4 planes into plane 0 (consecutive t: conflict-free)
#pragma unroll
    for (int d = 0; d < NC; ++d) {
        Hp[0][d][t] += (Hp[1][d][t] + Hp[2][d][t]) + Hp[3][d][t];
    }
    __syncthreads();

    // q-fold (verified in R5/R6): t -> (d = t>>4, c = t&15), coalesced store
    {
        const int d = t >> 4, c = t & 15;
        float rp = 0.f, rm = 0.f;
#pragma unroll
        for (int qi = 0; qi < NC; ++qi) rp += Hp[0][d][qi * NC + c];
#pragma unroll
        for (int qj = 0; qj < NC; ++qj) rm += Hp[0][d][c * NC + qj];
        wcd[n * NP + t] = rp - rm;
    }
}

// ---------------------------------------------------------------------------
// Kernel B: dx partials.  grid = 128 batches x 4 m-quarters, 256 threads.
// ---------------------------------------------------------------------------
__global__ __launch_bounds__(256) void k_dx(const float* __restrict__ cg_xyz,
                                            const float* __restrict__ wcd,
                                            const float* __restrict__ w1c,
                                            float* __restrict__ dxp) {
    __shared__ float xs[NC][4];
    __shared__ float cxs[64][4];
    const int b = blockIdx.x >> 2;
    const int q = blockIdx.x & 3;
    const int t = threadIdx.x;

    if (t < 48) xs[t / 3][t % 3] = cg_xyz[(size_t)b * NC * 3 + t];
    __syncthreads();
    if (t < 64) {
        const int m = q * 64 + t, c = m & 15, d = m >> 4;
        const float ax = xs[c][0], ay = xs[c][1], az = xs[c][2];
        const float bx = xs[d][0], by = xs[d][1], bz = xs[d][2];
        cxs[t][0] = ay * bz - az * by;
        cxs[t][1] = az * bx - ax * bz;
        cxs[t][2] = ax * by - ay * bx;
        cxs[t][3] = 0.f;
    }
    __syncthreads();

#pragma unroll
    for (int a = 0; a < 2; ++a) {
        const int n = a * 256 + t;
        const float4* __restrict__ w0 =
            (const float4*)(wcd + (size_t)n * NP + q * 64);
        float dx0 = 0.f, dx1 = 0.f, dx2 = 0.f;
#pragma unroll
        for (int k4 = 0; k4 < 16; ++k4) {
            const float4 w = w0[k4];
            const float4 c0 = *(const float4*)(&cxs[k4 * 4 + 0][0]);
            const float4 c1 = *(const float4*)(&cxs[k4 * 4 + 1][0]);
            const float4 c2 = *(const float4*)(&cxs[k4 * 4 + 2][0]);
            const float4 c3 = *(const float4*)(&cxs[k4 * 4 + 3][0]);
            dx0 += w.x * c0.x + w.y * c1.x + w.z * c2.x + w.w * c3.x;
            dx1 += w.x * c0.y + w.y * c1.y + w.z * c2.y + w.w * c3.y;
            dx2 += w.x * c0.z + w.y * c1.z + w.z * c2.z + w.w * c3.z;
        }
        if (q == 0) {
            const float* __restrict__ w1r = w1c + n * NC;
#pragma unroll
            for (int c = 0; c < NC; ++c) {
                const float wv = w1r[c];
                dx0 += wv * xs[c][0]; dx1 += wv * xs[c][1]; dx2 += wv * xs[c][2];
            }
        }
        float* __restrict__ op = dxp + (((size_t)q * NB + b) * NATOMS + n) * 3;
        op[0] = dx0; op[1] = dx1; op[2] = dx2;
    }
}

// ---------------------------------------------------------------------------
// Kernel C: finish.  grid = 128 batches, 512 threads (one per atom).
// ---------------------------------------------------------------------------
__global__ __launch_bounds__(512) void k_finish(const float* __restrict__ cg_xyz,
                                                const float* __restrict__ assign_norm,
                                                const int* __restrict__ assign_idx,
                                                const float* __restrict__ dxp,
                                                float* __restrict__ out_recon) {
    __shared__ float an_l[NATOMS][ANP];   // 43.0 KB
    __shared__ float dxl[NATOMS][DXP];    // 10.2 KB
    __shared__ float xs[NC][4];
    __shared__ float cgo_l[NC][4];
    const int b = blockIdx.x;
    const int t = threadIdx.x;

    {
        const float4* __restrict__ anr =
            (const float4*)(assign_norm + ((size_t)b * NATOMS + t) * NC);
#pragma unroll
        for (int i = 0; i < 4; ++i) {
            const float4 v = anr[i];
            an_l[t][4 * i + 0] = v.x; an_l[t][4 * i + 1] = v.y;
            an_l[t][4 * i + 2] = v.z; an_l[t][4 * i + 3] = v.w;
        }
    }
    if (t < 48) xs[t / 3][t % 3] = cg_xyz[(size_t)b * NC * 3 + t];

    float dx0, dx1, dx2;
    {
        const size_t s0 = (((size_t)0 * NB + b) * NATOMS + t) * 3;
        const size_t s1 = (((size_t)1 * NB + b) * NATOMS + t) * 3;
        const size_t s2 = (((size_t)2 * NB + b) * NATOMS + t) * 3;
        const size_t s3 = (((size_t)3 * NB + b) * NATOMS + t) * 3;
        dx0 = (dxp[s0 + 0] + dxp[s1 + 0]) + (dxp[s2 + 0] + dxp[s3 + 0]);
        dx1 = (dxp[s0 + 1] + dxp[s1 + 1]) + (dxp[s2 + 1] + dxp[s3 + 1]);
        dx2 = (dxp[s0 + 2] + dxp[s1 + 2]) + (dxp[s2 + 2] + dxp[s3 + 2]);
    }
    dxl[t][0] = dx0; dxl[t][1] = dx1; dxl[t][2] = dx2;
    __syncthreads();

    {
        const int j = t >> 5, g = t & 31;
        float p0 = 0.f, p1 = 0.f, p2 = 0.f;
#pragma unroll
        for (int k = 0; k < 16; ++k) {
            const int i = g + 32 * k;
            const float a = an_l[i][j];
            p0 += a * dxl[i][0];
            p1 += a * dxl[i][1];
            p2 += a * dxl[i][2];
        }
#pragma unroll
        for (int sh = 1; sh < 32; sh <<= 1) {
            p0 += __shfl_xor(p0, sh);
            p1 += __shfl_xor(p1, sh);
            p2 += __shfl_xor(p2, sh);
        }
        if (g == 0) { cgo_l[j][0] = p0; cgo_l[j][1] = p1; cgo_l[j][2] = p2; }
    }
    __syncthreads();

    const int ci = assign_idx[t];
    const float r0 = xs[ci][0] - cgo_l[ci][0] + dx0;
    const float r1 = xs[ci][1] - cgo_l[ci][1] + dx1;
    const float r2 = xs[ci][2] - cgo_l[ci][2] + dx2;
    const size_t ob = ((size_t)b * NATOMS + t) * 3;
    out_recon[ob + 0] = r0;
    out_recon[ob + 1] = r1;
    out_recon[ob + 2] = r2;
}

extern "C" void kernel_launch(void* const* d_in, const int* in_sizes, int n_in,
                              void* d_out, int out_size, void* d_ws, size_t ws_size,
                              hipStream_t stream) {
    (void)in_sizes; (void)n_in; (void)out_size; (void)ws_size;
    const float* soft_assign = (const float*)d_in[0];
    const float* xyz         = (const float*)d_in[1];
    const float* cg_xyz      = (const float*)d_in[2];
    const float* assign_norm = (const float*)d_in[3];
    const float* W           = (const float*)d_in[4];
    const int*   assign_idx  = (const int*)d_in[5];

    float* out       = (float*)d_out;
    float* out_sa    = out;                                   // 128*512*16
    float* out_xyz   = out + (size_t)NB * NATOMS * NC;        // 128*512*3
    float* out_recon = out_xyz + (size_t)NB * NATOMS * 3;

    float* wcd = (float*)d_ws;                                // 512*256
    float* w1c = wcd + (size_t)NATOMS * NP;                   // 512*16
    float* dxp = w1c + (size_t)NATOMS * NC;                   // 4*128*512*3

    k_stream<<<dim3(NATOMS), dim3(256), 0, stream>>>(W, soft_assign, xyz,
                                                     wcd, w1c, out_sa, out_xyz);
    k_dx<<<dim3(NB * 4), dim3(256), 0, stream>>>(cg_xyz, wcd, w1c, dxp);
    k_finish<<<dim3(NB), dim3(512), 0, stream>>>(cg_xyz, assign_norm, assign_idx,
                                                 dxp, out_recon);
}